// Round 1
// baseline (1735.532 us; speedup 1.0000x reference)
//
#include <hip/hip_runtime.h>
#include <hip/hip_bf16.h>
#include <math.h>

#define N_RESC 10000
#define N_EDGEC 320000
#define C_SC 384
#define C_ZC 128
#define C_HC 16
#define HC 12
#define PQC 4
#define PVC 8
#define PROJ_D 1152
#define QPR_D 144
#define KVPR_D 432
#define AGG_D 864
#define FEAT_D 960
#define OUT_D 384

// scales
#define S1C 0.14433756729740643f   /* sqrt(1/48) */
#define S2C 0.5773502691896258f    /* sqrt(1/3)  */
#define SHWC 0.13608276348795434f  /* sqrt(1/54) */

__global__ void k_zero(int* cursor) {
    int i = blockIdx.x * 256 + threadIdx.x;
    if (i < N_RESC) cursor[i] = 0;
}

__global__ void k_hist(const int* __restrict__ ei, int* cursor) {
    int e = blockIdx.x * 256 + threadIdx.x;
    if (e < N_EDGEC) atomicAdd(&cursor[ei[N_EDGEC + e]], 1);
}

// single-block exclusive scan of counts (in cursor) -> rowptr, and cursor := rowptr
__global__ __launch_bounds__(1024) void k_scan(int* cursor, int* rowptr) {
    __shared__ int buf[1024];
    __shared__ int carry_s;
    int t = threadIdx.x;
    if (t == 0) carry_s = 0;
    __syncthreads();
    for (int ch = 0; ch < 10; ++ch) {
        int idx = ch * 1024 + t;
        int v = (idx < N_RESC) ? cursor[idx] : 0;
        buf[t] = v;
        __syncthreads();
        for (int off = 1; off < 1024; off <<= 1) {
            int x = (t >= off) ? buf[t - off] : 0;
            __syncthreads();
            buf[t] += x;
            __syncthreads();
        }
        int incl = buf[t];
        int excl = incl - v;
        int base = carry_s;
        int total = buf[1023];
        if (idx < N_RESC) { rowptr[idx] = base + excl; cursor[idx] = base + excl; }
        __syncthreads();
        if (t == 0) carry_s = base + total;
        __syncthreads();
    }
    if (t == 0) rowptr[N_RESC] = carry_s;
}

__global__ void k_scatter(const int* __restrict__ ei, int* cursor, int* csr) {
    int e = blockIdx.x * 256 + threadIdx.x;
    if (e < N_EDGEC) {
        int d = ei[N_EDGEC + e];
        int pos = atomicAdd(&cursor[d], 1);
        csr[pos] = e;
    }
}

// ---- node projections: proj[n][1152] = s[n] @ [wq|wkv|wqp|wkvp] + biases ----
#define NT_P 16
__global__ __launch_bounds__(384) void k_proj(const float* __restrict__ s,
    const float* __restrict__ wq, const float* __restrict__ bq,
    const float* __restrict__ wkv, const float* __restrict__ bkv,
    const float* __restrict__ wqp, const float* __restrict__ bqp,
    const float* __restrict__ wkvp, const float* __restrict__ bkvp,
    float* __restrict__ proj) {
    __shared__ float sl[NT_P][C_SC];
    int t = threadIdx.x;
    int node0 = blockIdx.x * NT_P;
    for (int i = t; i < NT_P * C_SC; i += 384) {
        int nt = i / C_SC, j = i % C_SC;
        sl[nt][j] = s[(node0 + nt) * C_SC + j];
    }
    __syncthreads();
    const float* wp[3]; int st[3]; float bias[3]; int col[3];
    #pragma unroll
    for (int k = 0; k < 3; k++) {
        int c = t + k * 384; col[k] = c;
        if (c < 192)      { wp[k] = wq + c;          st[k] = 192; bias[k] = bq[c]; }
        else if (c < 576) { wp[k] = wkv + (c - 192); st[k] = 384; bias[k] = bkv[c - 192]; }
        else if (c < 720) { wp[k] = wqp + (c - 576); st[k] = 144; bias[k] = bqp[c - 576]; }
        else              { wp[k] = wkvp + (c - 720); st[k] = 432; bias[k] = bkvp[c - 720]; }
    }
    float acc[NT_P][3];
    #pragma unroll
    for (int nt = 0; nt < NT_P; nt++)
        #pragma unroll
        for (int k = 0; k < 3; k++) acc[nt][k] = 0.f;
    for (int j = 0; j < C_SC; j++) {
        float w0 = wp[0][j * st[0]];
        float w1 = wp[1][j * st[1]];
        float w2 = wp[2][j * st[2]];
        #pragma unroll
        for (int nt = 0; nt < NT_P; nt++) {
            float sv = sl[nt][j];
            acc[nt][0] += sv * w0;
            acc[nt][1] += sv * w1;
            acc[nt][2] += sv * w2;
        }
    }
    for (int nt = 0; nt < NT_P; nt++)
        #pragma unroll
        for (int k = 0; k < 3; k++)
            proj[(long)(node0 + nt) * PROJ_D + col[k]] = acc[nt][k] + bias[k];
}

// ---- rotate/translate raw point projections into global frame ----
__global__ __launch_bounds__(192) void k_rot(const float* __restrict__ proj,
    const float* __restrict__ rot, const float* __restrict__ trans,
    float* __restrict__ qpr, float* __restrict__ kvpr) {
    int n = blockIdx.x;
    int t = threadIdx.x;
    __shared__ float R[9], T[3];
    if (t < 9) R[t] = rot[n * 9 + t];
    if (t < 3) T[t] = trans[n * 3 + t];
    __syncthreads();
    const float* pr = proj + (long)n * PROJ_D;
    if (t < 48) {
        float x0 = pr[576 + t], x1 = pr[576 + 48 + t], x2 = pr[576 + 96 + t];
        #pragma unroll
        for (int i = 0; i < 3; i++)
            qpr[(long)n * QPR_D + t * 3 + i] = R[i*3+0]*x0 + R[i*3+1]*x1 + R[i*3+2]*x2 + T[i];
    } else {
        int p = t - 48;
        float x0 = pr[720 + p], x1 = pr[720 + 144 + p], x2 = pr[720 + 288 + p];
        #pragma unroll
        for (int i = 0; i < 3; i++)
            kvpr[(long)n * KVPR_D + p * 3 + i] = R[i*3+0]*x0 + R[i*3+1]*x1 + R[i*3+2]*x2 + T[i];
    }
}

// ---- per-edge: z projections (b, pair_z) + attention logits ----
__global__ __launch_bounds__(256) void k_edge(const float* __restrict__ z,
    const int* __restrict__ ei, const float* __restrict__ proj,
    const float* __restrict__ qpr, const float* __restrict__ kvpr,
    const float* __restrict__ mask,
    const float* __restrict__ wb, const float* __restrict__ bb,
    const float* __restrict__ wdz, const float* __restrict__ bdz,
    const float* __restrict__ head_w,
    float* __restrict__ alog, float* __restrict__ pairz) {
    __shared__ float zb[4][C_ZC];
    __shared__ float bbf[4][HC];
    int t = threadIdx.x;
    int w = t >> 6;
    int l = t & 63;
    long e = (long)blockIdx.x * 4 + w;   // grid = E/4 exactly
    zb[w][l] = z[e * C_ZC + l];
    zb[w][64 + l] = z[e * C_ZC + 64 + l];
    __syncthreads();
    if (l < 12) {
        float a = bb[l];
        for (int j = 0; j < C_ZC; j++) a += zb[w][j] * wb[j * 12 + l];
        bbf[w][l] = a;
    } else if (l < 44) {
        int c = l - 12;
        float a = bdz[c];
        for (int j = 0; j < C_ZC; j++) a += zb[w][j] * wdz[j * 32 + c];
        pairz[e * 32 + c] = a;
    }
    __syncthreads();
    int srcn = ei[e], dstn = ei[N_EDGEC + e];
    float emask = 100000.0f * (mask[srcn] * mask[dstn] - 1.0f);
    int c = l & 15;
    int hq = l >> 4;
    #pragma unroll
    for (int tp = 0; tp < 3; tp++) {
        int h = tp * 4 + hq;
        float qv = proj[(long)dstn * PROJ_D + h * 16 + c];
        float kv = proj[(long)srcn * PROJ_D + 192 + h * 32 + c];
        float val = S1C * qv * kv;
        if (c < 12) {
            int pq_ = c / 3, i = c % 3;
            float dq = qpr[(long)dstn * QPR_D + (h * 4 + pq_) * 3 + i];
            float dk = kvpr[(long)srcn * KVPR_D + (h * 12 + pq_) * 3 + i];
            float d = dq - dk;
            float hw = log1pf(expf(head_w[h])) * SHWC;
            val += -0.5f * hw * d * d;
        }
        #pragma unroll
        for (int off = 8; off >= 1; off >>= 1) val += __shfl_xor(val, off, 16);
        if (c == 0) alog[e * 12 + h] = val + S2C * bbf[w][h] + emask;
    }
}

// ---- per-node segment softmax + weighted aggregation (864 comps/node) ----
__global__ __launch_bounds__(256) void k_agg(const int* __restrict__ rowptr,
    const int* __restrict__ csr, const int* __restrict__ ei,
    const float* __restrict__ alog, const float* __restrict__ proj,
    const float* __restrict__ kvpr, const float* __restrict__ pairz,
    float* __restrict__ agg) {
    int n = blockIdx.x;
    int t = threadIdx.x;
    __shared__ float red[16 * 12];
    __shared__ float mh[12], linv[12];
    __shared__ float wl[16 * 12];
    __shared__ int el[16], sl_[16];
    int row0 = rowptr[n];
    int deg = rowptr[n + 1] - row0;
    int g = t >> 4, l16 = t & 15;
    float lm = -1e30f;
    if (l16 < 12) {
        for (int i = g; i < deg; i += 16) {
            int e = csr[row0 + i];
            lm = fmaxf(lm, alog[(long)e * 12 + l16]);
        }
        red[g * 12 + l16] = lm;
    }
    __syncthreads();
    if (t < 12) {
        float m = -1e30f;
        for (int gg = 0; gg < 16; gg++) m = fmaxf(m, red[gg * 12 + t]);
        mh[t] = m;
    }
    __syncthreads();
    if (l16 < 12) {
        float m = mh[l16];
        float ls = 0.f;
        for (int i = g; i < deg; i += 16) {
            int e = csr[row0 + i];
            ls += expf(alog[(long)e * 12 + l16] - m);
        }
        red[g * 12 + l16] = ls;
    }
    __syncthreads();
    if (t < 12) {
        float ssum = 0.f;
        for (int gg = 0; gg < 16; gg++) ssum += red[gg * 12 + t];
        linv[t] = 1.f / (ssum + 1e-16f);
    }
    __syncthreads();

    float acc[4] = {0.f, 0.f, 0.f, 0.f};
    int kind[4], off_[4], hk[4];
    #pragma unroll
    for (int k = 0; k < 4; k++) {
        int comp = t + k * 256;
        if (comp < 192)      { kind[k] = 0; int h = comp >> 4, cc = comp & 15; off_[k] = 192 + h * 32 + 16 + cc; hk[k] = h; }
        else if (comp < 480) { int idx = comp - 192; int p = idx / 3, i = idx % 3; int h = p >> 3, pv = p & 7;
                               kind[k] = 1; off_[k] = (h * 12 + 4 + pv) * 3 + i; hk[k] = h; }
        else if (comp < 864) { int idx = comp - 480; int h = idx >> 5, cc = idx & 31;
                               kind[k] = 2; off_[k] = cc; hk[k] = h; }
        else { kind[k] = 3; off_[k] = 0; hk[k] = 0; }
    }
    for (int cs = 0; cs < deg; cs += 16) {
        int cnt = min(16, deg - cs);
        __syncthreads();   // protect el/wl from previous chunk's readers
        if (t < 16) {
            int e = (t < cnt) ? csr[row0 + cs + t] : 0;
            el[t] = e;
            sl_[t] = ei[e];
        }
        __syncthreads();
        if (t < 192) {
            int i = t / 12, h = t % 12;
            if (i < cnt) {
                int e = el[i];
                wl[i * 12 + h] = expf(alog[(long)e * 12 + h] - mh[h]) * linv[h];
            }
        }
        __syncthreads();
        for (int i = 0; i < cnt; i++) {
            int e = el[i];
            int sn = sl_[i];
            #pragma unroll
            for (int k = 0; k < 4; k++) {
                if (kind[k] == 3) continue;
                float v;
                if (kind[k] == 0)      v = proj[(long)sn * PROJ_D + off_[k]];
                else if (kind[k] == 1) v = kvpr[(long)sn * KVPR_D + off_[k]];
                else                   v = pairz[(long)e * 32 + off_[k]];
                acc[k] += wl[i * 12 + hk[k]] * v;
            }
        }
    }
    #pragma unroll
    for (int k = 0; k < 4; k++) {
        int comp = t + k * 256;
        if (comp < AGG_D) agg[(long)n * AGG_D + comp] = acc[k];
    }
}

// ---- final: inverse-rotate o_pt, build feats, out = feats @ wout + bout ----
#define NT_F 8
__global__ __launch_bounds__(384) void k_final(const float* __restrict__ agg,
    const float* __restrict__ rot, const float* __restrict__ trans,
    const float* __restrict__ wout, const float* __restrict__ bout,
    float* __restrict__ out) {
    __shared__ float f[NT_F][FEAT_D];
    int t = threadIdx.x;
    int node0 = blockIdx.x * NT_F;
    for (int nt = 0; nt < NT_F; nt++) {
        int n = node0 + nt;
        const float* a = agg + (long)n * AGG_D;
        if (t < 192) {
            f[nt][t] = a[t];
        } else if (t < 288) {
            int p = t - 192;
            float gx = a[192 + p * 3 + 0] - trans[n * 3 + 0];
            float gy = a[192 + p * 3 + 1] - trans[n * 3 + 1];
            float gz = a[192 + p * 3 + 2] - trans[n * 3 + 2];
            const float* R = rot + (long)n * 9;
            float lx = R[0] * gx + R[3] * gy + R[6] * gz;
            float ly = R[1] * gx + R[4] * gy + R[7] * gz;
            float lz = R[2] * gx + R[5] * gy + R[8] * gz;
            f[nt][192 + p] = lx;
            f[nt][288 + p] = ly;
            f[nt][384 + p] = lz;
            f[nt][480 + p] = sqrtf(lx * lx + ly * ly + lz * lz + 1e-8f);
        } else {
            int q = t - 288;
            #pragma unroll
            for (int u = 0; u < 4; u++) f[nt][576 + q * 4 + u] = a[480 + q * 4 + u];
        }
    }
    __syncthreads();
    float acc[NT_F];
    #pragma unroll
    for (int nt = 0; nt < NT_F; nt++) acc[nt] = bout[t];
    for (int j = 0; j < FEAT_D; j++) {
        float wv = wout[j * OUT_D + t];
        #pragma unroll
        for (int nt = 0; nt < NT_F; nt++) acc[nt] += f[nt][j] * wv;
    }
    #pragma unroll
    for (int nt = 0; nt < NT_F; nt++)
        out[(long)(node0 + nt) * OUT_D + t] = acc[nt];
}

extern "C" void kernel_launch(void* const* d_in, const int* in_sizes, int n_in,
                              void* d_out, int out_size, void* d_ws, size_t ws_size,
                              hipStream_t stream) {
    const float* s     = (const float*)d_in[0];
    const float* z     = (const float*)d_in[1];
    const float* rot   = (const float*)d_in[2];
    const float* trans = (const float*)d_in[3];
    const float* mask  = (const float*)d_in[4];
    const int*   ei    = (const int*)d_in[5];
    const float* wq    = (const float*)d_in[6];
    const float* bq    = (const float*)d_in[7];
    const float* wkv   = (const float*)d_in[8];
    const float* bkv   = (const float*)d_in[9];
    const float* wqp   = (const float*)d_in[10];
    const float* bqp   = (const float*)d_in[11];
    const float* wkvp  = (const float*)d_in[12];
    const float* bkvp  = (const float*)d_in[13];
    const float* wb    = (const float*)d_in[14];
    const float* bb    = (const float*)d_in[15];
    const float* wdz   = (const float*)d_in[16];
    const float* bdz   = (const float*)d_in[17];
    const float* head_w= (const float*)d_in[18];
    const float* wout  = (const float*)d_in[19];
    const float* bout  = (const float*)d_in[20];
    float* out = (float*)d_out;

    float* ws    = (float*)d_ws;
    float* proj  = ws;                                   // 10000*1152 = 11,520,000
    float* qpr   = proj + (long)N_RESC * PROJ_D;         // 1,440,000
    float* kvpr  = qpr + (long)N_RESC * QPR_D;           // 4,320,000
    float* alog  = kvpr + (long)N_RESC * KVPR_D;         // 3,840,000
    float* pairz = alog + (long)N_EDGEC * 12;            // 10,240,000
    float* agg   = pairz + (long)N_EDGEC * 32;           // 8,640,000
    int* rowptr  = (int*)(agg + (long)N_RESC * AGG_D);   // 10001 (+pad)
    int* cursor  = rowptr + 10004;
    int* csr     = cursor + N_RESC;

    // CSR build by dst
    k_zero<<<(N_RESC + 255) / 256, 256, 0, stream>>>(cursor);
    k_hist<<<(N_EDGEC + 255) / 256, 256, 0, stream>>>(ei, cursor);
    k_scan<<<1, 1024, 0, stream>>>(cursor, rowptr);
    k_scatter<<<(N_EDGEC + 255) / 256, 256, 0, stream>>>(ei, cursor, csr);

    // node projections + point rotation
    k_proj<<<N_RESC / NT_P, 384, 0, stream>>>(s, wq, bq, wkv, bkv, wqp, bqp, wkvp, bkvp, proj);
    k_rot<<<N_RESC, 192, 0, stream>>>(proj, rot, trans, qpr, kvpr);

    // per-edge projections + logits
    k_edge<<<N_EDGEC / 4, 256, 0, stream>>>(z, ei, proj, qpr, kvpr, mask,
                                            wb, bb, wdz, bdz, head_w, alog, pairz);

    // per-node softmax + aggregation
    k_agg<<<N_RESC, 256, 0, stream>>>(rowptr, csr, ei, alog, proj, kvpr, pairz, agg);

    // final features + output GEMM
    k_final<<<N_RESC / NT_F, 384, 0, stream>>>(agg, rot, trans, wout, bout, out);
}

// Round 2
// 1388.221 us; speedup vs baseline: 1.2502x; 1.2502x over previous
//
#include <hip/hip_runtime.h>
#include <hip/hip_bf16.h>
#include <math.h>

#define N_RESC 10000
#define N_EDGEC 320000
#define C_SC 384
#define C_ZC 128
#define C_HC 16
#define HC 12
#define PQC 4
#define PVC 8
#define PROJ_D 1152
#define AGG_D 864
#define FEAT_D 960
#define OUT_D 384

// scales
#define S1C 0.14433756729740643f   /* sqrt(1/48) */
#define S2C 0.5773502691896258f    /* sqrt(1/3)  */
#define SHWC 0.13608276348795434f  /* sqrt(1/54) */

__global__ void k_zero(int* cursor) {
    int i = blockIdx.x * 256 + threadIdx.x;
    if (i < N_RESC) cursor[i] = 0;
}

__global__ void k_hist(const int* __restrict__ ei, int* cursor) {
    int e = blockIdx.x * 256 + threadIdx.x;
    if (e < N_EDGEC) atomicAdd(&cursor[ei[N_EDGEC + e]], 1);
}

// single-block exclusive scan of counts (in cursor) -> rowptr, and cursor := rowptr
__global__ __launch_bounds__(1024) void k_scan(int* cursor, int* rowptr) {
    __shared__ int buf[1024];
    __shared__ int carry_s;
    int t = threadIdx.x;
    if (t == 0) carry_s = 0;
    __syncthreads();
    for (int ch = 0; ch < 10; ++ch) {
        int idx = ch * 1024 + t;
        int v = (idx < N_RESC) ? cursor[idx] : 0;
        buf[t] = v;
        __syncthreads();
        for (int off = 1; off < 1024; off <<= 1) {
            int x = (t >= off) ? buf[t - off] : 0;
            __syncthreads();
            buf[t] += x;
            __syncthreads();
        }
        int incl = buf[t];
        int excl = incl - v;
        int base = carry_s;
        int total = buf[1023];
        if (idx < N_RESC) { rowptr[idx] = base + excl; cursor[idx] = base + excl; }
        __syncthreads();
        if (t == 0) carry_s = base + total;
        __syncthreads();
    }
    if (t == 0) rowptr[N_RESC] = carry_s;
}

__global__ void k_scatter(const int* __restrict__ ei, int* cursor, int* csr, int* src_csr) {
    int e = blockIdx.x * 256 + threadIdx.x;
    if (e < N_EDGEC) {
        int d = ei[N_EDGEC + e];
        int s = ei[e];
        int pos = atomicAdd(&cursor[d], 1);
        csr[pos] = e;
        src_csr[pos] = s;
    }
}

// ---- node projections into split layouts ----
#define NT_P 16
__global__ __launch_bounds__(384) void k_proj(const float* __restrict__ s,
    const float* __restrict__ wq, const float* __restrict__ bq,
    const float* __restrict__ wkv, const float* __restrict__ bkv,
    const float* __restrict__ wqp, const float* __restrict__ bqp,
    const float* __restrict__ wkvp, const float* __restrict__ bkvp,
    float* __restrict__ qh, float* __restrict__ kh, float* __restrict__ vh,
    float* __restrict__ praw) {
    __shared__ float sl[NT_P][C_SC];
    int t = threadIdx.x;
    int node0 = blockIdx.x * NT_P;
    for (int i = t; i < NT_P * C_SC; i += 384) {
        int nt = i / C_SC, j = i % C_SC;
        sl[nt][j] = s[(node0 + nt) * C_SC + j];
    }
    __syncthreads();
    const float* wp[3]; int st[3]; float bias[3]; int col[3];
    #pragma unroll
    for (int k = 0; k < 3; k++) {
        int c = t + k * 384; col[k] = c;
        if (c < 192)      { wp[k] = wq + c;          st[k] = 192; bias[k] = bq[c]; }
        else if (c < 576) { wp[k] = wkv + (c - 192); st[k] = 384; bias[k] = bkv[c - 192]; }
        else if (c < 720) { wp[k] = wqp + (c - 576); st[k] = 144; bias[k] = bqp[c - 576]; }
        else              { wp[k] = wkvp + (c - 720); st[k] = 432; bias[k] = bkvp[c - 720]; }
    }
    float acc[NT_P][3];
    #pragma unroll
    for (int nt = 0; nt < NT_P; nt++)
        #pragma unroll
        for (int k = 0; k < 3; k++) acc[nt][k] = 0.f;
    for (int j = 0; j < C_SC; j++) {
        float w0 = wp[0][j * st[0]];
        float w1 = wp[1][j * st[1]];
        float w2 = wp[2][j * st[2]];
        #pragma unroll
        for (int nt = 0; nt < NT_P; nt++) {
            float sv = sl[nt][j];
            acc[nt][0] += sv * w0;
            acc[nt][1] += sv * w1;
            acc[nt][2] += sv * w2;
        }
    }
    for (int nt = 0; nt < NT_P; nt++) {
        int n = node0 + nt;
        #pragma unroll
        for (int k = 0; k < 3; k++) {
            float val = acc[nt][k] + bias[k];
            int c = col[k];
            if (c < 192) qh[(long)n * 192 + c] = val;
            else if (c < 576) {
                int cc = c - 192; int h = cc >> 5, r = cc & 31;
                if (r < 16) kh[(long)n * 192 + h * 16 + r] = val;
                else        vh[(long)n * 192 + h * 16 + (r - 16)] = val;
            } else praw[(long)n * 576 + (c - 576)] = val;
        }
    }
}

// ---- rotate/translate raw point projections into global frame, split layouts ----
__global__ __launch_bounds__(192) void k_rot(const float* __restrict__ praw,
    const float* __restrict__ rot, const float* __restrict__ trans,
    float* __restrict__ qpts, float* __restrict__ kpts, float* __restrict__ vpts) {
    int n = blockIdx.x;
    int t = threadIdx.x;
    __shared__ float R[9], T[3];
    if (t < 9) R[t] = rot[n * 9 + t];
    if (t < 3) T[t] = trans[n * 3 + t];
    __syncthreads();
    const float* pr = praw + (long)n * 576;
    if (t < 48) {
        float x0 = pr[t], x1 = pr[48 + t], x2 = pr[96 + t];
        #pragma unroll
        for (int i = 0; i < 3; i++)
            qpts[(long)n * 144 + t * 3 + i] = R[i*3+0]*x0 + R[i*3+1]*x1 + R[i*3+2]*x2 + T[i];
    } else {
        int p = t - 48;   // 0..143 = h*12+pp
        float x0 = pr[144 + p], x1 = pr[288 + p], x2 = pr[432 + p];
        int h = p / 12, pp = p % 12;
        #pragma unroll
        for (int i = 0; i < 3; i++) {
            float val = R[i*3+0]*x0 + R[i*3+1]*x1 + R[i*3+2]*x2 + T[i];
            if (pp < 4) kpts[(long)n * 144 + (h * 4 + pp) * 3 + i] = val;
            else        vpts[(long)n * 288 + (h * 8 + (pp - 4)) * 3 + i] = val;
        }
    }
}

// ---- edge GEMM: [b_e | pairz] = z @ [wb | wdz] + bias ; one edge per thread ----
__global__ __launch_bounds__(256) void k_zproj(const float* __restrict__ z,
    const float* __restrict__ wb, const float* __restrict__ bb,
    const float* __restrict__ wdz, const float* __restrict__ bdz,
    float* __restrict__ b_e, float* __restrict__ pairz) {
    __shared__ float wl[C_ZC * 44];
    int t = threadIdx.x;
    for (int i = t; i < C_ZC * 44; i += 256) {
        int j = i / 44, c = i % 44;
        wl[i] = (c < 12) ? wb[j * 12 + c] : wdz[j * 32 + (c - 12)];
    }
    __syncthreads();
    long e = (long)blockIdx.x * 256 + t;
    float4 acc4[11];
    #pragma unroll
    for (int q = 0; q < 11; q++) {
        int c = q * 4;
        acc4[q].x = (c + 0 < 12) ? bb[c + 0] : bdz[c - 12 + 0];
        acc4[q].y = (c + 1 < 12) ? bb[c + 1] : bdz[c - 12 + 1];
        acc4[q].z = (c + 2 < 12) ? bb[c + 2] : bdz[c - 12 + 2];
        acc4[q].w = (c + 3 < 12) ? bb[c - 12 + 3 < 0 ? c + 3 : c + 3] : bdz[c - 12 + 3];
    }
    const float4* zrow = reinterpret_cast<const float4*>(z + e * C_ZC);
    const float4* wl4 = reinterpret_cast<const float4*>(wl);
    for (int j4 = 0; j4 < 32; j4++) {
        float4 zv = zrow[j4];
        #pragma unroll
        for (int u = 0; u < 4; u++) {
            float zs = (u == 0) ? zv.x : (u == 1) ? zv.y : (u == 2) ? zv.z : zv.w;
            int j = j4 * 4 + u;
            #pragma unroll
            for (int q = 0; q < 11; q++) {
                float4 wv = wl4[j * 11 + q];
                acc4[q].x += zs * wv.x;
                acc4[q].y += zs * wv.y;
                acc4[q].z += zs * wv.z;
                acc4[q].w += zs * wv.w;
            }
        }
    }
    float4* bo = reinterpret_cast<float4*>(b_e + e * 12);
    bo[0] = acc4[0]; bo[1] = acc4[1]; bo[2] = acc4[2];
    float4* po = reinterpret_cast<float4*>(pairz + e * 32);
    #pragma unroll
    for (int q = 3; q < 11; q++) po[q - 3] = acc4[q];
}

// ---- logits in CSR (dst) order: q staged per node, dense k gathers ----
__global__ __launch_bounds__(256) void k_logit(const int* __restrict__ rowptr,
    const int* __restrict__ csr, const int* __restrict__ src_csr,
    const float* __restrict__ qh, const float* __restrict__ kh,
    const float* __restrict__ qpts, const float* __restrict__ kpts,
    const float* __restrict__ mask, const float* __restrict__ head_w,
    const float* __restrict__ b_e, float* __restrict__ alog) {
    int n = blockIdx.x;
    int t = threadIdx.x;
    __shared__ float qf[192], qp[144], hws[12];
    if (t < 192) qf[t] = qh[(long)n * 192 + t];
    if (t < 144) qp[t] = qpts[(long)n * 144 + t];
    if (t < 12)  hws[t] = log1pf(expf(head_w[t])) * SHWC;
    float mdst = mask[n];
    __syncthreads();
    int row0 = rowptr[n];
    int deg = rowptr[n + 1] - row0;
    int w = t >> 6, l = t & 63, c = l & 15, hq = l >> 4;
    for (int i = w; i < deg; i += 4) {
        int pos = row0 + i;
        int src = src_csr[pos];
        int e = csr[pos];
        float em = 100000.0f * (mask[src] * mdst - 1.0f);
        #pragma unroll
        for (int tp = 0; tp < 3; tp++) {
            int h = tp * 4 + hq;
            float val = S1C * qf[h * 16 + c] * kh[(long)src * 192 + tp * 64 + l];
            if (c < 12) {
                float d = qp[h * 12 + c] - kpts[(long)src * 144 + h * 12 + c];
                val = fmaf(-0.5f * hws[h] * d, d, val);
            }
            val += __shfl_xor(val, 8, 16);
            val += __shfl_xor(val, 4, 16);
            val += __shfl_xor(val, 2, 16);
            val += __shfl_xor(val, 1, 16);
            if (c == 0) alog[(long)pos * 12 + h] = val + S2C * b_e[(long)e * 12 + h] + em;
        }
    }
}

// ---- per-node segment softmax + weighted aggregation (864 comps/node) ----
__global__ __launch_bounds__(256) void k_agg(const int* __restrict__ rowptr,
    const int* __restrict__ csr, const int* __restrict__ src_csr,
    const float* __restrict__ alog, const float* __restrict__ vh,
    const float* __restrict__ vpts, const float* __restrict__ pairz,
    float* __restrict__ agg) {
    int n = blockIdx.x;
    int t = threadIdx.x;
    __shared__ float red[16 * 12];
    __shared__ float mh[12], linv[12];
    __shared__ float wl[16 * 12];
    __shared__ int el[16], sl_[16];
    int row0 = rowptr[n];
    int deg = rowptr[n + 1] - row0;
    int g = t >> 4, l16 = t & 15;
    float lm = -1e30f;
    if (l16 < 12) {
        for (int i = g; i < deg; i += 16)
            lm = fmaxf(lm, alog[(long)(row0 + i) * 12 + l16]);
        red[g * 12 + l16] = lm;
    }
    __syncthreads();
    if (t < 12) {
        float m = -1e30f;
        for (int gg = 0; gg < 16; gg++) m = fmaxf(m, red[gg * 12 + t]);
        mh[t] = m;
    }
    __syncthreads();
    if (l16 < 12) {
        float m = mh[l16];
        float ls = 0.f;
        for (int i = g; i < deg; i += 16)
            ls += expf(alog[(long)(row0 + i) * 12 + l16] - m);
        red[g * 12 + l16] = ls;
    }
    __syncthreads();
    if (t < 12) {
        float ssum = 0.f;
        for (int gg = 0; gg < 16; gg++) ssum += red[gg * 12 + t];
        linv[t] = 1.f / (ssum + 1e-16f);
    }
    __syncthreads();

    float acc[4] = {0.f, 0.f, 0.f, 0.f};
    int kind[4], off_[4], hk[4];
    #pragma unroll
    for (int k = 0; k < 4; k++) {
        int comp = t + k * 256;
        if (comp < 192)      { kind[k] = 0; off_[k] = comp; hk[k] = comp >> 4; }
        else if (comp < 480) { int idx = comp - 192; kind[k] = 1; off_[k] = idx; hk[k] = idx / 24; }
        else if (comp < 864) { int idx = comp - 480; kind[k] = 2; off_[k] = idx & 31; hk[k] = idx >> 5; }
        else { kind[k] = 3; off_[k] = 0; hk[k] = 0; }
    }
    for (int cs = 0; cs < deg; cs += 16) {
        int cnt = min(16, deg - cs);
        __syncthreads();
        if (t < 16) {
            int p = (t < cnt) ? (row0 + cs + t) : row0;
            el[t] = csr[p];
            sl_[t] = src_csr[p];
        }
        __syncthreads();
        if (t < 192) {
            int i = t / 12, h = t % 12;
            if (i < cnt)
                wl[t] = expf(alog[(long)(row0 + cs) * 12 + t] - mh[h]) * linv[h];
        }
        __syncthreads();
        for (int i = 0; i < cnt; i++) {
            int e = el[i];
            int sn = sl_[i];
            #pragma unroll
            for (int k = 0; k < 4; k++) {
                if (kind[k] == 3) continue;
                float v;
                if (kind[k] == 0)      v = vh[(long)sn * 192 + off_[k]];
                else if (kind[k] == 1) v = vpts[(long)sn * 288 + off_[k]];
                else                   v = pairz[(long)e * 32 + off_[k]];
                acc[k] += wl[i * 12 + hk[k]] * v;
            }
        }
    }
    #pragma unroll
    for (int k = 0; k < 4; k++) {
        int comp = t + k * 256;
        if (comp < AGG_D) agg[(long)n * AGG_D + comp] = acc[k];
    }
}

// ---- final: inverse-rotate o_pt, build feats, out = feats @ wout + bout ----
#define NT_F 8
__global__ __launch_bounds__(384) void k_final(const float* __restrict__ agg,
    const float* __restrict__ rot, const float* __restrict__ trans,
    const float* __restrict__ wout, const float* __restrict__ bout,
    float* __restrict__ out) {
    __shared__ float f[NT_F][FEAT_D];
    int t = threadIdx.x;
    int node0 = blockIdx.x * NT_F;
    for (int nt = 0; nt < NT_F; nt++) {
        int n = node0 + nt;
        const float* a = agg + (long)n * AGG_D;
        if (t < 192) {
            f[nt][t] = a[t];
        } else if (t < 288) {
            int p = t - 192;
            float gx = a[192 + p * 3 + 0] - trans[n * 3 + 0];
            float gy = a[192 + p * 3 + 1] - trans[n * 3 + 1];
            float gz = a[192 + p * 3 + 2] - trans[n * 3 + 2];
            const float* R = rot + (long)n * 9;
            float lx = R[0] * gx + R[3] * gy + R[6] * gz;
            float ly = R[1] * gx + R[4] * gy + R[7] * gz;
            float lz = R[2] * gx + R[5] * gy + R[8] * gz;
            f[nt][192 + p] = lx;
            f[nt][288 + p] = ly;
            f[nt][384 + p] = lz;
            f[nt][480 + p] = sqrtf(lx * lx + ly * ly + lz * lz + 1e-8f);
        } else {
            int q = t - 288;
            #pragma unroll
            for (int u = 0; u < 4; u++) f[nt][576 + q * 4 + u] = a[480 + q * 4 + u];
        }
    }
    __syncthreads();
    float acc[NT_F];
    #pragma unroll
    for (int nt = 0; nt < NT_F; nt++) acc[nt] = bout[t];
    for (int j = 0; j < FEAT_D; j++) {
        float wv = wout[j * OUT_D + t];
        #pragma unroll
        for (int nt = 0; nt < NT_F; nt++) acc[nt] += f[nt][j] * wv;
    }
    #pragma unroll
    for (int nt = 0; nt < NT_F; nt++)
        out[(long)(node0 + nt) * OUT_D + t] = acc[nt];
}

extern "C" void kernel_launch(void* const* d_in, const int* in_sizes, int n_in,
                              void* d_out, int out_size, void* d_ws, size_t ws_size,
                              hipStream_t stream) {
    const float* s     = (const float*)d_in[0];
    const float* z     = (const float*)d_in[1];
    const float* rot   = (const float*)d_in[2];
    const float* trans = (const float*)d_in[3];
    const float* mask  = (const float*)d_in[4];
    const int*   ei    = (const int*)d_in[5];
    const float* wq    = (const float*)d_in[6];
    const float* bq    = (const float*)d_in[7];
    const float* wkv   = (const float*)d_in[8];
    const float* bkv   = (const float*)d_in[9];
    const float* wqp   = (const float*)d_in[10];
    const float* bqp   = (const float*)d_in[11];
    const float* wkvp  = (const float*)d_in[12];
    const float* bkvp  = (const float*)d_in[13];
    const float* wb    = (const float*)d_in[14];
    const float* bb    = (const float*)d_in[15];
    const float* wdz   = (const float*)d_in[16];
    const float* bdz   = (const float*)d_in[17];
    const float* head_w= (const float*)d_in[18];
    const float* wout  = (const float*)d_in[19];
    const float* bout  = (const float*)d_in[20];
    float* out = (float*)d_out;

    float* ws    = (float*)d_ws;
    float* qh    = ws;                         // 1,920,000
    float* kh    = qh + 1920000;               // 1,920,000
    float* vh    = kh + 1920000;               // 1,920,000
    float* qpts  = vh + 1920000;               // 1,440,000
    float* kpts  = qpts + 1440000;             // 1,440,000
    float* vpts  = kpts + 1440000;             // 2,880,000
    float* b_e   = vpts + 2880000;             // 3,840,000
    float* pairz = b_e + 3840000;              // 10,240,000
    float* alog  = pairz + 10240000;           // 3,840,000
    float* agg   = alog + 3840000;             // 8,640,000
    float* praw  = agg;                        // alias: praw (5.76M) lives inside agg region
    int* rowptr  = (int*)(agg + 8640000);      // 10001 (+pad)
    int* cursor  = rowptr + 10004;
    int* csr     = cursor + 10000;
    int* src_csr = csr + N_EDGEC;

    // CSR build by dst
    k_zero<<<(N_RESC + 255) / 256, 256, 0, stream>>>(cursor);
    k_hist<<<(N_EDGEC + 255) / 256, 256, 0, stream>>>(ei, cursor);
    k_scan<<<1, 1024, 0, stream>>>(cursor, rowptr);
    k_scatter<<<(N_EDGEC + 255) / 256, 256, 0, stream>>>(ei, cursor, csr, src_csr);

    // node projections + point rotation (praw consumed before agg is written)
    k_proj<<<N_RESC / NT_P, 384, 0, stream>>>(s, wq, bq, wkv, bkv, wqp, bqp, wkvp, bkvp,
                                              qh, kh, vh, praw);
    k_rot<<<N_RESC, 192, 0, stream>>>(praw, rot, trans, qpts, kpts, vpts);

    // edge z-projection GEMM
    k_zproj<<<N_EDGEC / 256, 256, 0, stream>>>(z, wb, bb, wdz, bdz, b_e, pairz);

    // logits in CSR order
    k_logit<<<N_RESC, 256, 0, stream>>>(rowptr, csr, src_csr, qh, kh, qpts, kpts,
                                        mask, head_w, b_e, alog);

    // per-node softmax + aggregation
    k_agg<<<N_RESC, 256, 0, stream>>>(rowptr, csr, src_csr, alog, vh, vpts, pairz, agg);

    // final features + output GEMM
    k_final<<<N_RESC / NT_F, 384, 0, stream>>>(agg, rot, trans, wout, bout, out);
}

// Round 3
// 1285.206 us; speedup vs baseline: 1.3504x; 1.0802x over previous
//
#include <hip/hip_runtime.h>
#include <hip/hip_bf16.h>
#include <math.h>

#define N_RESC 10000
#define N_EDGEC 320000
#define C_SC 384
#define C_ZC 128
#define AGG_D 864
#define FEAT_D 960
#define OUT_D 384

// scales
#define S1C 0.14433756729740643f   /* sqrt(1/48) */
#define S2C 0.5773502691896258f    /* sqrt(1/3)  */
#define SHWC 0.13608276348795434f  /* sqrt(1/54) */

__global__ void k_zero(int* cursor) {
    int i = blockIdx.x * 256 + threadIdx.x;
    if (i < N_RESC) cursor[i] = 0;
}

__global__ void k_hist(const int* __restrict__ ei, int* cursor) {
    int e = blockIdx.x * 256 + threadIdx.x;
    if (e < N_EDGEC) atomicAdd(&cursor[ei[N_EDGEC + e]], 1);
}

__global__ __launch_bounds__(1024) void k_scan(int* cursor, int* rowptr) {
    __shared__ int buf[1024];
    __shared__ int carry_s;
    int t = threadIdx.x;
    if (t == 0) carry_s = 0;
    __syncthreads();
    for (int ch = 0; ch < 10; ++ch) {
        int idx = ch * 1024 + t;
        int v = (idx < N_RESC) ? cursor[idx] : 0;
        buf[t] = v;
        __syncthreads();
        for (int off = 1; off < 1024; off <<= 1) {
            int x = (t >= off) ? buf[t - off] : 0;
            __syncthreads();
            buf[t] += x;
            __syncthreads();
        }
        int incl = buf[t];
        int excl = incl - v;
        int base = carry_s;
        int total = buf[1023];
        if (idx < N_RESC) { rowptr[idx] = base + excl; cursor[idx] = base + excl; }
        __syncthreads();
        if (t == 0) carry_s = base + total;
        __syncthreads();
    }
    if (t == 0) rowptr[N_RESC] = carry_s;
}

__global__ void k_scatter(const int* __restrict__ ei, int* cursor, int* csr, int* src_csr) {
    int e = blockIdx.x * 256 + threadIdx.x;
    if (e < N_EDGEC) {
        int d = ei[N_EDGEC + e];
        int s = ei[e];
        int pos = atomicAdd(&cursor[d], 1);
        csr[pos] = e;
        src_csr[pos] = s;
    }
}

// ---- node projections into split layouts ----
#define NT_P 16
__global__ __launch_bounds__(384) void k_proj(const float* __restrict__ s,
    const float* __restrict__ wq, const float* __restrict__ bq,
    const float* __restrict__ wkv, const float* __restrict__ bkv,
    const float* __restrict__ wqp, const float* __restrict__ bqp,
    const float* __restrict__ wkvp, const float* __restrict__ bkvp,
    float* __restrict__ qh, float* __restrict__ kh, float* __restrict__ vh,
    float* __restrict__ praw) {
    __shared__ float sl[NT_P][C_SC];
    int t = threadIdx.x;
    int node0 = blockIdx.x * NT_P;
    for (int i = t; i < NT_P * C_SC; i += 384) {
        int nt = i / C_SC, j = i % C_SC;
        sl[nt][j] = s[(node0 + nt) * C_SC + j];
    }
    __syncthreads();
    const float* wp[3]; int st[3]; float bias[3]; int col[3];
    #pragma unroll
    for (int k = 0; k < 3; k++) {
        int c = t + k * 384; col[k] = c;
        if (c < 192)      { wp[k] = wq + c;          st[k] = 192; bias[k] = bq[c]; }
        else if (c < 576) { wp[k] = wkv + (c - 192); st[k] = 384; bias[k] = bkv[c - 192]; }
        else if (c < 720) { wp[k] = wqp + (c - 576); st[k] = 144; bias[k] = bqp[c - 576]; }
        else              { wp[k] = wkvp + (c - 720); st[k] = 432; bias[k] = bkvp[c - 720]; }
    }
    float acc[NT_P][3];
    #pragma unroll
    for (int nt = 0; nt < NT_P; nt++)
        #pragma unroll
        for (int k = 0; k < 3; k++) acc[nt][k] = 0.f;
    for (int j = 0; j < C_SC; j += 4) {
        float4 sv4[NT_P];
        #pragma unroll
        for (int nt = 0; nt < NT_P; nt++) sv4[nt] = *(const float4*)&sl[nt][j];
        #pragma unroll
        for (int u = 0; u < 4; u++) {
            float w0 = wp[0][(j + u) * st[0]];
            float w1 = wp[1][(j + u) * st[1]];
            float w2 = wp[2][(j + u) * st[2]];
            #pragma unroll
            for (int nt = 0; nt < NT_P; nt++) {
                float sv = (u == 0) ? sv4[nt].x : (u == 1) ? sv4[nt].y : (u == 2) ? sv4[nt].z : sv4[nt].w;
                acc[nt][0] = fmaf(sv, w0, acc[nt][0]);
                acc[nt][1] = fmaf(sv, w1, acc[nt][1]);
                acc[nt][2] = fmaf(sv, w2, acc[nt][2]);
            }
        }
    }
    for (int nt = 0; nt < NT_P; nt++) {
        int n = node0 + nt;
        #pragma unroll
        for (int k = 0; k < 3; k++) {
            float val = acc[nt][k] + bias[k];
            int c = col[k];
            if (c < 192) qh[(long)n * 192 + c] = val;
            else if (c < 576) {
                int cc = c - 192; int h = cc >> 5, r = cc & 31;
                if (r < 16) kh[(long)n * 192 + h * 16 + r] = val;
                else        vh[(long)n * 192 + h * 16 + (r - 16)] = val;
            } else praw[(long)n * 576 + (c - 576)] = val;
        }
    }
}

// ---- rotate/translate raw point projections into global frame, split layouts ----
__global__ __launch_bounds__(192) void k_rot(const float* __restrict__ praw,
    const float* __restrict__ rot, const float* __restrict__ trans,
    float* __restrict__ qpts, float* __restrict__ kpts, float* __restrict__ vpts) {
    int n = blockIdx.x;
    int t = threadIdx.x;
    __shared__ float R[9], T[3];
    if (t < 9) R[t] = rot[n * 9 + t];
    if (t < 3) T[t] = trans[n * 3 + t];
    __syncthreads();
    const float* pr = praw + (long)n * 576;
    if (t < 48) {
        float x0 = pr[t], x1 = pr[48 + t], x2 = pr[96 + t];
        #pragma unroll
        for (int i = 0; i < 3; i++)
            qpts[(long)n * 144 + t * 3 + i] = R[i*3+0]*x0 + R[i*3+1]*x1 + R[i*3+2]*x2 + T[i];
    } else {
        int p = t - 48;   // 0..143 = h*12+pp
        float x0 = pr[144 + p], x1 = pr[288 + p], x2 = pr[432 + p];
        int h = p / 12, pp = p % 12;
        #pragma unroll
        for (int i = 0; i < 3; i++) {
            float val = R[i*3+0]*x0 + R[i*3+1]*x1 + R[i*3+2]*x2 + T[i];
            if (pp < 4) kpts[(long)n * 144 + (h * 4 + pp) * 3 + i] = val;
            else        vpts[(long)n * 288 + (h * 8 + (pp - 4)) * 3 + i] = val;
        }
    }
}

// ---- edge GEMM: [b_e | pairz] = z @ [wb | wdz] + bias ----
// weights read with wave-uniform indices -> compiler emits s_load + SGPR-operand FMA
__global__ __launch_bounds__(256) void k_zproj(const float* __restrict__ z,
    const float* __restrict__ wb, const float* __restrict__ bb,
    const float* __restrict__ wdz, const float* __restrict__ bdz,
    float* __restrict__ b_e, float* __restrict__ pairz) {
    int t = threadIdx.x;
    long e = (long)blockIdx.x * 256 + t;
    float acc[44];
    #pragma unroll
    for (int c = 0; c < 12; c++) acc[c] = bb[c];
    #pragma unroll
    for (int c = 0; c < 32; c++) acc[12 + c] = bdz[c];
    const float4* zrow = reinterpret_cast<const float4*>(z + e * C_ZC);
    for (int j4 = 0; j4 < 32; j4++) {
        float4 zv = zrow[j4];
        #pragma unroll
        for (int u = 0; u < 4; u++) {
            float zs = (u == 0) ? zv.x : (u == 1) ? zv.y : (u == 2) ? zv.z : zv.w;
            int j = j4 * 4 + u;
            #pragma unroll
            for (int c = 0; c < 12; c++) acc[c] = fmaf(zs, wb[j * 12 + c], acc[c]);
            #pragma unroll
            for (int c = 0; c < 32; c++) acc[12 + c] = fmaf(zs, wdz[j * 32 + c], acc[12 + c]);
        }
    }
    float4* bo = reinterpret_cast<float4*>(b_e + e * 12);
    #pragma unroll
    for (int q = 0; q < 3; q++)
        bo[q] = make_float4(acc[q*4], acc[q*4+1], acc[q*4+2], acc[q*4+3]);
    float4* po = reinterpret_cast<float4*>(pairz + e * 32);
    #pragma unroll
    for (int q = 0; q < 8; q++)
        po[q] = make_float4(acc[12+q*4], acc[12+q*4+1], acc[12+q*4+2], acc[12+q*4+3]);
}

// ---- logits in CSR (dst) order: q staged per node, dense k gathers ----
__global__ __launch_bounds__(256) void k_logit(const int* __restrict__ rowptr,
    const int* __restrict__ csr, const int* __restrict__ src_csr,
    const float* __restrict__ qh, const float* __restrict__ kh,
    const float* __restrict__ qpts, const float* __restrict__ kpts,
    const float* __restrict__ mask, const float* __restrict__ head_w,
    const float* __restrict__ b_e, float* __restrict__ alog) {
    int n = blockIdx.x;
    int t = threadIdx.x;
    __shared__ float qf[192], qp[144], hws[12];
    if (t < 192) qf[t] = qh[(long)n * 192 + t];
    if (t < 144) qp[t] = qpts[(long)n * 144 + t];
    if (t < 12)  hws[t] = log1pf(expf(head_w[t])) * SHWC;
    float mdst = mask[n];
    __syncthreads();
    int row0 = rowptr[n];
    int deg = rowptr[n + 1] - row0;
    int w = t >> 6, l = t & 63, c = l & 15, hq = l >> 4;
    for (int i = w; i < deg; i += 4) {
        int pos = row0 + i;
        int src = src_csr[pos];
        int e = csr[pos];
        float em = 100000.0f * (mask[src] * mdst - 1.0f);
        #pragma unroll
        for (int tp = 0; tp < 3; tp++) {
            int h = tp * 4 + hq;
            float val = S1C * qf[h * 16 + c] * kh[(long)src * 192 + tp * 64 + l];
            if (c < 12) {
                float d = qp[h * 12 + c] - kpts[(long)src * 144 + h * 12 + c];
                val = fmaf(-0.5f * hws[h] * d, d, val);
            }
            val += __shfl_xor(val, 8, 16);
            val += __shfl_xor(val, 4, 16);
            val += __shfl_xor(val, 2, 16);
            val += __shfl_xor(val, 1, 16);
            if (c == 0) alog[(long)pos * 12 + h] = val + S2C * b_e[(long)e * 12 + h] + em;
        }
    }
}

// ---- per-node segment softmax + weighted aggregation, float4 per thread ----
#define CAPE 256
__global__ __launch_bounds__(256) void k_agg(const int* __restrict__ rowptr,
    const int* __restrict__ csr, const int* __restrict__ src_csr,
    const float* __restrict__ alog, const float* __restrict__ vh,
    const float* __restrict__ vpts, const float* __restrict__ pairz,
    float* __restrict__ agg) {
    int n = blockIdx.x;
    int t = threadIdx.x;
    __shared__ float red[16 * 12];
    __shared__ float mh[12], linv[12];
    __shared__ float al[CAPE * 12];
    __shared__ int el[CAPE], sl_[CAPE];
    int row0 = rowptr[n];
    int deg = rowptr[n + 1] - row0;
    int g = t >> 4, l16 = t & 15;
    // phase A: per-head max and sum-exp (global alog reads, coalesced-ish)
    if (l16 < 12) {
        float lm = -1e30f;
        for (int i = g; i < deg; i += 16)
            lm = fmaxf(lm, alog[(long)(row0 + i) * 12 + l16]);
        red[g * 12 + l16] = lm;
    }
    __syncthreads();
    if (t < 12) {
        float m = -1e30f;
        for (int gg = 0; gg < 16; gg++) m = fmaxf(m, red[gg * 12 + t]);
        mh[t] = m;
    }
    __syncthreads();
    if (l16 < 12) {
        float m = mh[l16];
        float ls = 0.f;
        for (int i = g; i < deg; i += 16)
            ls += expf(alog[(long)(row0 + i) * 12 + l16] - m);
        red[g * 12 + l16] = ls;
    }
    __syncthreads();
    if (t < 12) {
        float ssum = 0.f;
        for (int gg = 0; gg < 16; gg++) ssum += red[gg * 12 + t];
        linv[t] = 1.f / (ssum + 1e-16f);
    }

    // component mapping: thread t < 216 owns comps [4t, 4t+4)
    const float* base = nullptr;
    int scale = 0, hk = 0, use_e = 0;
    int comp = t * 4;
    if (comp < 192)      { base = vh + comp; scale = 192; hk = comp >> 4; }
    else if (comp < 480) { int idx = comp - 192; base = vpts + idx; scale = 288; hk = idx / 24; }
    else if (comp < 864) { int idx = comp - 480; base = pairz + (idx & 31); scale = 32; hk = idx >> 5; use_e = 1; }
    float4 acc = make_float4(0.f, 0.f, 0.f, 0.f);

    for (int cs = 0; cs < deg; cs += CAPE) {
        int cnt = min(CAPE, deg - cs);
        __syncthreads();
        for (int i = t; i < cnt * 12; i += 256) {
            int h = i % 12;
            al[i] = expf(alog[(long)(row0 + cs) * 12 + i] - mh[h]) * linv[h];
        }
        for (int i = t; i < cnt; i += 256) {
            int p = row0 + cs + i;
            el[i] = csr[p];
            sl_[i] = src_csr[p];
        }
        __syncthreads();
        if (t < 216) {
            int i = 0;
            for (; i + 4 <= cnt; i += 4) {
                int i0 = use_e ? el[i] : sl_[i];
                int i1 = use_e ? el[i+1] : sl_[i+1];
                int i2 = use_e ? el[i+2] : sl_[i+2];
                int i3 = use_e ? el[i+3] : sl_[i+3];
                float4 v0 = *(const float4*)(base + (long)i0 * scale);
                float4 v1 = *(const float4*)(base + (long)i1 * scale);
                float4 v2 = *(const float4*)(base + (long)i2 * scale);
                float4 v3 = *(const float4*)(base + (long)i3 * scale);
                float w0 = al[i * 12 + hk];
                float w1 = al[(i+1) * 12 + hk];
                float w2 = al[(i+2) * 12 + hk];
                float w3 = al[(i+3) * 12 + hk];
                acc.x = fmaf(w0, v0.x, acc.x); acc.y = fmaf(w0, v0.y, acc.y);
                acc.z = fmaf(w0, v0.z, acc.z); acc.w = fmaf(w0, v0.w, acc.w);
                acc.x = fmaf(w1, v1.x, acc.x); acc.y = fmaf(w1, v1.y, acc.y);
                acc.z = fmaf(w1, v1.z, acc.z); acc.w = fmaf(w1, v1.w, acc.w);
                acc.x = fmaf(w2, v2.x, acc.x); acc.y = fmaf(w2, v2.y, acc.y);
                acc.z = fmaf(w2, v2.z, acc.z); acc.w = fmaf(w2, v2.w, acc.w);
                acc.x = fmaf(w3, v3.x, acc.x); acc.y = fmaf(w3, v3.y, acc.y);
                acc.z = fmaf(w3, v3.z, acc.z); acc.w = fmaf(w3, v3.w, acc.w);
            }
            for (; i < cnt; i++) {
                int ii = use_e ? el[i] : sl_[i];
                float4 v = *(const float4*)(base + (long)ii * scale);
                float w = al[i * 12 + hk];
                acc.x = fmaf(w, v.x, acc.x); acc.y = fmaf(w, v.y, acc.y);
                acc.z = fmaf(w, v.z, acc.z); acc.w = fmaf(w, v.w, acc.w);
            }
        }
    }
    if (t < 216) *(float4*)(agg + (long)n * AGG_D + comp) = acc;
}

// ---- final: inverse-rotate o_pt, build feats, out = feats @ wout + bout ----
#define NT_F 8
__global__ __launch_bounds__(384) void k_final(const float* __restrict__ agg,
    const float* __restrict__ rot, const float* __restrict__ trans,
    const float* __restrict__ wout, const float* __restrict__ bout,
    float* __restrict__ out) {
    __shared__ float f[NT_F][FEAT_D];
    int t = threadIdx.x;
    int node0 = blockIdx.x * NT_F;
    for (int nt = 0; nt < NT_F; nt++) {
        int n = node0 + nt;
        const float* a = agg + (long)n * AGG_D;
        if (t < 192) {
            f[nt][t] = a[t];
        } else if (t < 288) {
            int p = t - 192;
            float gx = a[192 + p * 3 + 0] - trans[n * 3 + 0];
            float gy = a[192 + p * 3 + 1] - trans[n * 3 + 1];
            float gz = a[192 + p * 3 + 2] - trans[n * 3 + 2];
            const float* R = rot + (long)n * 9;
            float lx = R[0] * gx + R[3] * gy + R[6] * gz;
            float ly = R[1] * gx + R[4] * gy + R[7] * gz;
            float lz = R[2] * gx + R[5] * gy + R[8] * gz;
            f[nt][192 + p] = lx;
            f[nt][288 + p] = ly;
            f[nt][384 + p] = lz;
            f[nt][480 + p] = sqrtf(lx * lx + ly * ly + lz * lz + 1e-8f);
        } else {
            int q = t - 288;
            #pragma unroll
            for (int u = 0; u < 4; u++) f[nt][576 + q * 4 + u] = a[480 + q * 4 + u];
        }
    }
    __syncthreads();
    float acc[NT_F];
    #pragma unroll
    for (int nt = 0; nt < NT_F; nt++) acc[nt] = bout[t];
    for (int j = 0; j < FEAT_D; j += 4) {
        float4 fv[NT_F];
        #pragma unroll
        for (int nt = 0; nt < NT_F; nt++) fv[nt] = *(const float4*)&f[nt][j];
        #pragma unroll
        for (int u = 0; u < 4; u++) {
            float wv = wout[(j + u) * OUT_D + t];
            #pragma unroll
            for (int nt = 0; nt < NT_F; nt++) {
                float fvu = (u == 0) ? fv[nt].x : (u == 1) ? fv[nt].y : (u == 2) ? fv[nt].z : fv[nt].w;
                acc[nt] = fmaf(fvu, wv, acc[nt]);
            }
        }
    }
    #pragma unroll
    for (int nt = 0; nt < NT_F; nt++)
        out[(long)(node0 + nt) * OUT_D + t] = acc[nt];
}

extern "C" void kernel_launch(void* const* d_in, const int* in_sizes, int n_in,
                              void* d_out, int out_size, void* d_ws, size_t ws_size,
                              hipStream_t stream) {
    const float* s     = (const float*)d_in[0];
    const float* z     = (const float*)d_in[1];
    const float* rot   = (const float*)d_in[2];
    const float* trans = (const float*)d_in[3];
    const float* mask  = (const float*)d_in[4];
    const int*   ei    = (const int*)d_in[5];
    const float* wq    = (const float*)d_in[6];
    const float* bq    = (const float*)d_in[7];
    const float* wkv   = (const float*)d_in[8];
    const float* bkv   = (const float*)d_in[9];
    const float* wqp   = (const float*)d_in[10];
    const float* bqp   = (const float*)d_in[11];
    const float* wkvp  = (const float*)d_in[12];
    const float* bkvp  = (const float*)d_in[13];
    const float* wb    = (const float*)d_in[14];
    const float* bb    = (const float*)d_in[15];
    const float* wdz   = (const float*)d_in[16];
    const float* bdz   = (const float*)d_in[17];
    const float* head_w= (const float*)d_in[18];
    const float* wout  = (const float*)d_in[19];
    const float* bout  = (const float*)d_in[20];
    float* out = (float*)d_out;

    float* ws    = (float*)d_ws;
    float* qh    = ws;                         // 1,920,000
    float* kh    = qh + 1920000;               // 1,920,000
    float* vh    = kh + 1920000;               // 1,920,000
    float* qpts  = vh + 1920000;               // 1,440,000
    float* kpts  = qpts + 1440000;             // 1,440,000
    float* vpts  = kpts + 1440000;             // 2,880,000
    float* b_e   = vpts + 2880000;             // 3,840,000
    float* pairz = b_e + 3840000;              // 10,240,000
    float* alog  = pairz + 10240000;           // 3,840,000
    float* agg   = alog + 3840000;             // 8,640,000
    float* praw  = agg;                        // alias: praw (5.76M) lives inside agg region
    int* rowptr  = (int*)(agg + 8640000);      // 10001 (+pad)
    int* cursor  = rowptr + 10004;
    int* csr     = cursor + 10000;
    int* src_csr = csr + N_EDGEC;

    // CSR build by dst
    k_zero<<<(N_RESC + 255) / 256, 256, 0, stream>>>(cursor);
    k_hist<<<(N_EDGEC + 255) / 256, 256, 0, stream>>>(ei, cursor);
    k_scan<<<1, 1024, 0, stream>>>(cursor, rowptr);
    k_scatter<<<(N_EDGEC + 255) / 256, 256, 0, stream>>>(ei, cursor, csr, src_csr);

    // node projections + point rotation (praw consumed before agg is written)
    k_proj<<<N_RESC / NT_P, 384, 0, stream>>>(s, wq, bq, wkv, bkv, wqp, bqp, wkvp, bkvp,
                                              qh, kh, vh, praw);
    k_rot<<<N_RESC, 192, 0, stream>>>(praw, rot, trans, qpts, kpts, vpts);

    // edge z-projection GEMM
    k_zproj<<<N_EDGEC / 256, 256, 0, stream>>>(z, wb, bb, wdz, bdz, b_e, pairz);

    // logits in CSR order
    k_logit<<<N_RESC, 256, 0, stream>>>(rowptr, csr, src_csr, qh, kh, qpts, kpts,
                                        mask, head_w, b_e, alog);

    // per-node softmax + aggregation
    k_agg<<<N_RESC, 256, 0, stream>>>(rowptr, csr, src_csr, alog, vh, vpts, pairz, agg);

    // final features + output GEMM
    k_final<<<N_RESC / NT_F, 384, 0, stream>>>(agg, rot, trans, wout, bout, out);
}

// Round 4
// 1121.261 us; speedup vs baseline: 1.5478x; 1.1462x over previous
//
#include <hip/hip_runtime.h>
#include <hip/hip_bf16.h>
#include <math.h>

#define N_RESC 10000
#define N_EDGEC 320000
#define C_SC 384
#define C_ZC 128
#define AGG_D 864
#define FEAT_D 960
#define OUT_D 384

// scales
#define S1C 0.14433756729740643f   /* sqrt(1/48) */
#define S2C 0.5773502691896258f    /* sqrt(1/3)  */
#define SHWC 0.13608276348795434f  /* sqrt(1/54) */

__global__ void k_zero(int* cursor) {
    int i = blockIdx.x * 256 + threadIdx.x;
    if (i < N_RESC) cursor[i] = 0;
}

__global__ void k_hist(const int* __restrict__ ei, int* cursor) {
    int e = blockIdx.x * 256 + threadIdx.x;
    if (e < N_EDGEC) atomicAdd(&cursor[ei[N_EDGEC + e]], 1);
}

__global__ __launch_bounds__(1024) void k_scan(int* cursor, int* rowptr) {
    __shared__ int buf[1024];
    __shared__ int carry_s;
    int t = threadIdx.x;
    if (t == 0) carry_s = 0;
    __syncthreads();
    for (int ch = 0; ch < 10; ++ch) {
        int idx = ch * 1024 + t;
        int v = (idx < N_RESC) ? cursor[idx] : 0;
        buf[t] = v;
        __syncthreads();
        for (int off = 1; off < 1024; off <<= 1) {
            int x = (t >= off) ? buf[t - off] : 0;
            __syncthreads();
            buf[t] += x;
            __syncthreads();
        }
        int incl = buf[t];
        int excl = incl - v;
        int base = carry_s;
        int total = buf[1023];
        if (idx < N_RESC) { rowptr[idx] = base + excl; cursor[idx] = base + excl; }
        __syncthreads();
        if (t == 0) carry_s = base + total;
        __syncthreads();
    }
    if (t == 0) rowptr[N_RESC] = carry_s;
}

__global__ void k_scatter(const int* __restrict__ ei, int* cursor, int* csr, int* src_csr) {
    int e = blockIdx.x * 256 + threadIdx.x;
    if (e < N_EDGEC) {
        int d = ei[N_EDGEC + e];
        int s = ei[e];
        int pos = atomicAdd(&cursor[d], 1);
        csr[pos] = e;
        src_csr[pos] = s;
    }
}

// ---- node projections into split layouts ----
// NT_P=8: grid 1250 blocks (vs 625) -> occupancy fix; LDS 12 KB
#define NT_P 8
__global__ __launch_bounds__(384) void k_proj(const float* __restrict__ s,
    const float* __restrict__ wq, const float* __restrict__ bq,
    const float* __restrict__ wkv, const float* __restrict__ bkv,
    const float* __restrict__ wqp, const float* __restrict__ bqp,
    const float* __restrict__ wkvp, const float* __restrict__ bkvp,
    float* __restrict__ qh, float* __restrict__ kh, float* __restrict__ vh,
    float* __restrict__ praw) {
    __shared__ float sl[NT_P][C_SC];
    int t = threadIdx.x;
    int node0 = blockIdx.x * NT_P;
    for (int i = t; i < NT_P * C_SC; i += 384) {
        int nt = i / C_SC, j = i % C_SC;
        sl[nt][j] = s[(node0 + nt) * C_SC + j];
    }
    __syncthreads();
    const float* wp[3]; int st[3]; float bias[3]; int col[3];
    #pragma unroll
    for (int k = 0; k < 3; k++) {
        int c = t + k * 384; col[k] = c;
        if (c < 192)      { wp[k] = wq + c;          st[k] = 192; bias[k] = bq[c]; }
        else if (c < 576) { wp[k] = wkv + (c - 192); st[k] = 384; bias[k] = bkv[c - 192]; }
        else if (c < 720) { wp[k] = wqp + (c - 576); st[k] = 144; bias[k] = bqp[c - 576]; }
        else              { wp[k] = wkvp + (c - 720); st[k] = 432; bias[k] = bkvp[c - 720]; }
    }
    float acc[NT_P][3];
    #pragma unroll
    for (int nt = 0; nt < NT_P; nt++)
        #pragma unroll
        for (int k = 0; k < 3; k++) acc[nt][k] = 0.f;
    for (int j = 0; j < C_SC; j += 4) {
        float4 sv4[NT_P];
        #pragma unroll
        for (int nt = 0; nt < NT_P; nt++) sv4[nt] = *(const float4*)&sl[nt][j];
        #pragma unroll
        for (int u = 0; u < 4; u++) {
            float w0 = wp[0][(j + u) * st[0]];
            float w1 = wp[1][(j + u) * st[1]];
            float w2 = wp[2][(j + u) * st[2]];
            #pragma unroll
            for (int nt = 0; nt < NT_P; nt++) {
                float sv = (u == 0) ? sv4[nt].x : (u == 1) ? sv4[nt].y : (u == 2) ? sv4[nt].z : sv4[nt].w;
                acc[nt][0] = fmaf(sv, w0, acc[nt][0]);
                acc[nt][1] = fmaf(sv, w1, acc[nt][1]);
                acc[nt][2] = fmaf(sv, w2, acc[nt][2]);
            }
        }
    }
    for (int nt = 0; nt < NT_P; nt++) {
        int n = node0 + nt;
        #pragma unroll
        for (int k = 0; k < 3; k++) {
            float val = acc[nt][k] + bias[k];
            int c = col[k];
            if (c < 192) qh[(long)n * 192 + c] = val;
            else if (c < 576) {
                int cc = c - 192; int h = cc >> 5, r = cc & 31;
                if (r < 16) kh[(long)n * 192 + h * 16 + r] = val;
                else        vh[(long)n * 192 + h * 16 + (r - 16)] = val;
            } else praw[(long)n * 576 + (c - 576)] = val;
        }
    }
}

// ---- rotate/translate raw point projections into global frame, split layouts ----
__global__ __launch_bounds__(192) void k_rot(const float* __restrict__ praw,
    const float* __restrict__ rot, const float* __restrict__ trans,
    float* __restrict__ qpts, float* __restrict__ kpts, float* __restrict__ vpts) {
    int n = blockIdx.x;
    int t = threadIdx.x;
    __shared__ float R[9], T[3];
    if (t < 9) R[t] = rot[n * 9 + t];
    if (t < 3) T[t] = trans[n * 3 + t];
    __syncthreads();
    const float* pr = praw + (long)n * 576;
    if (t < 48) {
        float x0 = pr[t], x1 = pr[48 + t], x2 = pr[96 + t];
        #pragma unroll
        for (int i = 0; i < 3; i++)
            qpts[(long)n * 144 + t * 3 + i] = R[i*3+0]*x0 + R[i*3+1]*x1 + R[i*3+2]*x2 + T[i];
    } else {
        int p = t - 48;   // 0..143 = h*12+pp
        float x0 = pr[144 + p], x1 = pr[288 + p], x2 = pr[432 + p];
        int h = p / 12, pp = p % 12;
        #pragma unroll
        for (int i = 0; i < 3; i++) {
            float val = R[i*3+0]*x0 + R[i*3+1]*x1 + R[i*3+2]*x2 + T[i];
            if (pp < 4) kpts[(long)n * 144 + (h * 4 + pp) * 3 + i] = val;
            else        vpts[(long)n * 288 + (h * 8 + (pp - 4)) * 3 + i] = val;
        }
    }
}

// ---- edge GEMM: [b_e | pairz] = z @ [wb | wdz] + bias ----
__global__ __launch_bounds__(256) void k_zproj(const float* __restrict__ z,
    const float* __restrict__ wb, const float* __restrict__ bb,
    const float* __restrict__ wdz, const float* __restrict__ bdz,
    float* __restrict__ b_e, float* __restrict__ pairz) {
    int t = threadIdx.x;
    long e = (long)blockIdx.x * 256 + t;
    float acc[44];
    #pragma unroll
    for (int c = 0; c < 12; c++) acc[c] = bb[c];
    #pragma unroll
    for (int c = 0; c < 32; c++) acc[12 + c] = bdz[c];
    const float4* zrow = reinterpret_cast<const float4*>(z + e * C_ZC);
    for (int j4 = 0; j4 < 32; j4++) {
        float4 zv = zrow[j4];
        #pragma unroll
        for (int u = 0; u < 4; u++) {
            float zs = (u == 0) ? zv.x : (u == 1) ? zv.y : (u == 2) ? zv.z : zv.w;
            int j = j4 * 4 + u;
            #pragma unroll
            for (int c = 0; c < 12; c++) acc[c] = fmaf(zs, wb[j * 12 + c], acc[c]);
            #pragma unroll
            for (int c = 0; c < 32; c++) acc[12 + c] = fmaf(zs, wdz[j * 32 + c], acc[12 + c]);
        }
    }
    float4* bo = reinterpret_cast<float4*>(b_e + e * 12);
    #pragma unroll
    for (int q = 0; q < 3; q++)
        bo[q] = make_float4(acc[q*4], acc[q*4+1], acc[q*4+2], acc[q*4+3]);
    float4* po = reinterpret_cast<float4*>(pairz + e * 32);
    #pragma unroll
    for (int q = 0; q < 8; q++)
        po[q] = make_float4(acc[12+q*4], acc[12+q*4+1], acc[12+q*4+2], acc[12+q*4+3]);
}

// ---- logits in CSR (dst) order: q staged per node, dense k gathers ----
__global__ __launch_bounds__(256) void k_logit(const int* __restrict__ rowptr,
    const int* __restrict__ csr, const int* __restrict__ src_csr,
    const float* __restrict__ qh, const float* __restrict__ kh,
    const float* __restrict__ qpts, const float* __restrict__ kpts,
    const float* __restrict__ mask, const float* __restrict__ head_w,
    const float* __restrict__ b_e, float* __restrict__ alog) {
    int n = blockIdx.x;
    int t = threadIdx.x;
    __shared__ float qf[192], qp[144], hws[12];
    if (t < 192) qf[t] = qh[(long)n * 192 + t];
    if (t < 144) qp[t] = qpts[(long)n * 144 + t];
    if (t < 12)  hws[t] = log1pf(expf(head_w[t])) * SHWC;
    float mdst = mask[n];
    __syncthreads();
    int row0 = rowptr[n];
    int deg = rowptr[n + 1] - row0;
    int w = t >> 6, l = t & 63, c = l & 15, hq = l >> 4;
    for (int i = w; i < deg; i += 4) {
        int pos = row0 + i;
        int src = src_csr[pos];
        int e = csr[pos];
        float em = 100000.0f * (mask[src] * mdst - 1.0f);
        #pragma unroll
        for (int tp = 0; tp < 3; tp++) {
            int h = tp * 4 + hq;
            float val = S1C * qf[h * 16 + c] * kh[(long)src * 192 + tp * 64 + l];
            if (c < 12) {
                float d = qp[h * 12 + c] - kpts[(long)src * 144 + h * 12 + c];
                val = fmaf(-0.5f * hws[h] * d, d, val);
            }
            val += __shfl_xor(val, 8, 16);
            val += __shfl_xor(val, 4, 16);
            val += __shfl_xor(val, 2, 16);
            val += __shfl_xor(val, 1, 16);
            if (c == 0) alog[(long)pos * 12 + h] = val + S2C * b_e[(long)e * 12 + h] + em;
        }
    }
}

// ---- per-node segment softmax + weighted aggregation, float4 per thread ----
#define CAPE 256
__global__ __launch_bounds__(256) void k_agg(const int* __restrict__ rowptr,
    const int* __restrict__ csr, const int* __restrict__ src_csr,
    const float* __restrict__ alog, const float* __restrict__ vh,
    const float* __restrict__ vpts, const float* __restrict__ pairz,
    float* __restrict__ agg) {
    int n = blockIdx.x;
    int t = threadIdx.x;
    __shared__ float red[16 * 12];
    __shared__ float mh[12], linv[12];
    __shared__ float al[CAPE * 12];
    __shared__ int el[CAPE], sl_[CAPE];
    int row0 = rowptr[n];
    int deg = rowptr[n + 1] - row0;
    int g = t >> 4, l16 = t & 15;
    if (l16 < 12) {
        float lm = -1e30f;
        for (int i = g; i < deg; i += 16)
            lm = fmaxf(lm, alog[(long)(row0 + i) * 12 + l16]);
        red[g * 12 + l16] = lm;
    }
    __syncthreads();
    if (t < 12) {
        float m = -1e30f;
        for (int gg = 0; gg < 16; gg++) m = fmaxf(m, red[gg * 12 + t]);
        mh[t] = m;
    }
    __syncthreads();
    if (l16 < 12) {
        float m = mh[l16];
        float ls = 0.f;
        for (int i = g; i < deg; i += 16)
            ls += expf(alog[(long)(row0 + i) * 12 + l16] - m);
        red[g * 12 + l16] = ls;
    }
    __syncthreads();
    if (t < 12) {
        float ssum = 0.f;
        for (int gg = 0; gg < 16; gg++) ssum += red[gg * 12 + t];
        linv[t] = 1.f / (ssum + 1e-16f);
    }

    const float* base = nullptr;
    int scale = 0, hk = 0, use_e = 0;
    int comp = t * 4;
    if (comp < 192)      { base = vh + comp; scale = 192; hk = comp >> 4; }
    else if (comp < 480) { int idx = comp - 192; base = vpts + idx; scale = 288; hk = idx / 24; }
    else if (comp < 864) { int idx = comp - 480; base = pairz + (idx & 31); scale = 32; hk = idx >> 5; use_e = 1; }
    float4 acc = make_float4(0.f, 0.f, 0.f, 0.f);

    for (int cs = 0; cs < deg; cs += CAPE) {
        int cnt = min(CAPE, deg - cs);
        __syncthreads();
        for (int i = t; i < cnt * 12; i += 256) {
            int h = i % 12;
            al[i] = expf(alog[(long)(row0 + cs) * 12 + i] - mh[h]) * linv[h];
        }
        for (int i = t; i < cnt; i += 256) {
            int p = row0 + cs + i;
            el[i] = csr[p];
            sl_[i] = src_csr[p];
        }
        __syncthreads();
        if (t < 216) {
            int i = 0;
            for (; i + 4 <= cnt; i += 4) {
                int i0 = use_e ? el[i] : sl_[i];
                int i1 = use_e ? el[i+1] : sl_[i+1];
                int i2 = use_e ? el[i+2] : sl_[i+2];
                int i3 = use_e ? el[i+3] : sl_[i+3];
                float4 v0 = *(const float4*)(base + (long)i0 * scale);
                float4 v1 = *(const float4*)(base + (long)i1 * scale);
                float4 v2 = *(const float4*)(base + (long)i2 * scale);
                float4 v3 = *(const float4*)(base + (long)i3 * scale);
                float w0 = al[i * 12 + hk];
                float w1 = al[(i+1) * 12 + hk];
                float w2 = al[(i+2) * 12 + hk];
                float w3 = al[(i+3) * 12 + hk];
                acc.x = fmaf(w0, v0.x, acc.x); acc.y = fmaf(w0, v0.y, acc.y);
                acc.z = fmaf(w0, v0.z, acc.z); acc.w = fmaf(w0, v0.w, acc.w);
                acc.x = fmaf(w1, v1.x, acc.x); acc.y = fmaf(w1, v1.y, acc.y);
                acc.z = fmaf(w1, v1.z, acc.z); acc.w = fmaf(w1, v1.w, acc.w);
                acc.x = fmaf(w2, v2.x, acc.x); acc.y = fmaf(w2, v2.y, acc.y);
                acc.z = fmaf(w2, v2.z, acc.z); acc.w = fmaf(w2, v2.w, acc.w);
                acc.x = fmaf(w3, v3.x, acc.x); acc.y = fmaf(w3, v3.y, acc.y);
                acc.z = fmaf(w3, v3.z, acc.z); acc.w = fmaf(w3, v3.w, acc.w);
            }
            for (; i < cnt; i++) {
                int ii = use_e ? el[i] : sl_[i];
                float4 v = *(const float4*)(base + (long)ii * scale);
                float w = al[i * 12 + hk];
                acc.x = fmaf(w, v.x, acc.x); acc.y = fmaf(w, v.y, acc.y);
                acc.z = fmaf(w, v.z, acc.z); acc.w = fmaf(w, v.w, acc.w);
            }
        }
    }
    if (t < 216) *(float4*)(agg + (long)n * AGG_D + comp) = acc;
}

// ---- final: inverse-rotate o_pt, build feats, out = feats @ wout + bout ----
// 192 threads, 2 output cols per thread -> VALU-bound (was LDS-issue-bound)
#define NT_F 8
__global__ __launch_bounds__(192) void k_final(const float* __restrict__ agg,
    const float* __restrict__ rot, const float* __restrict__ trans,
    const float* __restrict__ wout, const float* __restrict__ bout,
    float* __restrict__ out) {
    __shared__ float f[NT_F][FEAT_D];
    int t = threadIdx.x;
    int node0 = blockIdx.x * NT_F;
    for (int idx = t; idx < NT_F * 192; idx += 192) {
        int nt = idx / 192, c = idx % 192;
        f[nt][c] = agg[(long)(node0 + nt) * AGG_D + c];
    }
    for (int idx = t; idx < NT_F * 96; idx += 192) {
        int nt = idx / 96, p = idx % 96;
        int n = node0 + nt;
        const float* a = agg + (long)n * AGG_D;
        float gx = a[192 + p * 3 + 0] - trans[n * 3 + 0];
        float gy = a[192 + p * 3 + 1] - trans[n * 3 + 1];
        float gz = a[192 + p * 3 + 2] - trans[n * 3 + 2];
        const float* R = rot + (long)n * 9;
        float lx = R[0] * gx + R[3] * gy + R[6] * gz;
        float ly = R[1] * gx + R[4] * gy + R[7] * gz;
        float lz = R[2] * gx + R[5] * gy + R[8] * gz;
        f[nt][192 + p] = lx;
        f[nt][288 + p] = ly;
        f[nt][384 + p] = lz;
        f[nt][480 + p] = sqrtf(lx * lx + ly * ly + lz * lz + 1e-8f);
    }
    for (int idx = t; idx < NT_F * 384; idx += 192) {
        int nt = idx / 384, q = idx % 384;
        f[nt][576 + q] = agg[(long)(node0 + nt) * AGG_D + 480 + q];
    }
    __syncthreads();
    float acc0[NT_F], acc1[NT_F];
    float b0 = bout[t], b1 = bout[t + 192];
    #pragma unroll
    for (int nt = 0; nt < NT_F; nt++) { acc0[nt] = b0; acc1[nt] = b1; }
    for (int j = 0; j < FEAT_D; j += 4) {
        float4 fv[NT_F];
        #pragma unroll
        for (int nt = 0; nt < NT_F; nt++) fv[nt] = *(const float4*)&f[nt][j];
        #pragma unroll
        for (int u = 0; u < 4; u++) {
            float w0 = wout[(j + u) * OUT_D + t];
            float w1 = wout[(j + u) * OUT_D + t + 192];
            #pragma unroll
            for (int nt = 0; nt < NT_F; nt++) {
                float fvu = (u == 0) ? fv[nt].x : (u == 1) ? fv[nt].y : (u == 2) ? fv[nt].z : fv[nt].w;
                acc0[nt] = fmaf(fvu, w0, acc0[nt]);
                acc1[nt] = fmaf(fvu, w1, acc1[nt]);
            }
        }
    }
    #pragma unroll
    for (int nt = 0; nt < NT_F; nt++) {
        out[(long)(node0 + nt) * OUT_D + t] = acc0[nt];
        out[(long)(node0 + nt) * OUT_D + t + 192] = acc1[nt];
    }
}

extern "C" void kernel_launch(void* const* d_in, const int* in_sizes, int n_in,
                              void* d_out, int out_size, void* d_ws, size_t ws_size,
                              hipStream_t stream) {
    const float* s     = (const float*)d_in[0];
    const float* z     = (const float*)d_in[1];
    const float* rot   = (const float*)d_in[2];
    const float* trans = (const float*)d_in[3];
    const float* mask  = (const float*)d_in[4];
    const int*   ei    = (const int*)d_in[5];
    const float* wq    = (const float*)d_in[6];
    const float* bq    = (const float*)d_in[7];
    const float* wkv   = (const float*)d_in[8];
    const float* bkv   = (const float*)d_in[9];
    const float* wqp   = (const float*)d_in[10];
    const float* bqp   = (const float*)d_in[11];
    const float* wkvp  = (const float*)d_in[12];
    const float* bkvp  = (const float*)d_in[13];
    const float* wb    = (const float*)d_in[14];
    const float* bb    = (const float*)d_in[15];
    const float* wdz   = (const float*)d_in[16];
    const float* bdz   = (const float*)d_in[17];
    const float* head_w= (const float*)d_in[18];
    const float* wout  = (const float*)d_in[19];
    const float* bout  = (const float*)d_in[20];
    float* out = (float*)d_out;

    float* ws    = (float*)d_ws;
    float* qh    = ws;                         // 1,920,000
    float* kh    = qh + 1920000;               // 1,920,000
    float* vh    = kh + 1920000;               // 1,920,000
    float* qpts  = vh + 1920000;               // 1,440,000
    float* kpts  = qpts + 1440000;             // 1,440,000
    float* vpts  = kpts + 1440000;             // 2,880,000
    float* b_e   = vpts + 2880000;             // 3,840,000
    float* pairz = b_e + 3840000;              // 10,240,000
    float* alog  = pairz + 10240000;           // 3,840,000
    float* agg   = alog + 3840000;             // 8,640,000
    float* praw  = agg;                        // alias: praw (5.76M) lives inside agg region
    int* rowptr  = (int*)(agg + 8640000);      // 10001 (+pad)
    int* cursor  = rowptr + 10004;
    int* csr     = cursor + 10000;
    int* src_csr = csr + N_EDGEC;

    // CSR build by dst
    k_zero<<<(N_RESC + 255) / 256, 256, 0, stream>>>(cursor);
    k_hist<<<(N_EDGEC + 255) / 256, 256, 0, stream>>>(ei, cursor);
    k_scan<<<1, 1024, 0, stream>>>(cursor, rowptr);
    k_scatter<<<(N_EDGEC + 255) / 256, 256, 0, stream>>>(ei, cursor, csr, src_csr);

    // node projections + point rotation (praw consumed before agg is written)
    k_proj<<<N_RESC / NT_P, 384, 0, stream>>>(s, wq, bq, wkv, bkv, wqp, bqp, wkvp, bkvp,
                                              qh, kh, vh, praw);
    k_rot<<<N_RESC, 192, 0, stream>>>(praw, rot, trans, qpts, kpts, vpts);

    // edge z-projection GEMM
    k_zproj<<<N_EDGEC / 256, 256, 0, stream>>>(z, wb, bb, wdz, bdz, b_e, pairz);

    // logits in CSR order
    k_logit<<<N_RESC, 256, 0, stream>>>(rowptr, csr, src_csr, qh, kh, qpts, kpts,
                                        mask, head_w, b_e, alog);

    // per-node softmax + aggregation
    k_agg<<<N_RESC, 256, 0, stream>>>(rowptr, csr, src_csr, alog, vh, vpts, pairz, agg);

    // final features + output GEMM
    k_final<<<N_RESC / NT_F, 192, 0, stream>>>(agg, rot, trans, wout, bout, out);
}